// Round 5
// baseline (107.093 us; speedup 1.0000x reference)
//
#include <hip/hip_runtime.h>
#include <math.h>

#define BATCH 2
#define NPTS  1024
#define NC    32
#define DIN   8
#define DOUT  8
#define TA    4                               // a's per thread
#define OUT_ELEMS (BATCH * NPTS * DOUT)       // 16384

// RNE pack fp32 -> bf16 bits (no dependence on __hip_bfloat16 API).
__device__ __forceinline__ unsigned short pack_bf16(float s) {
    unsigned u = __float_as_uint(s);
    u += 0x7fffu + ((u >> 16) & 1u);          // round-to-nearest-even
    return (unsigned short)(u >> 16);
}

// ---------------------------------------------------------------------------
// conv_partial: block = (z, chunk). Stage g[b,c,i] (bf16) for BCHUNK b's into
// LDS, then thread t accumulates TA=4 a's over all (b,c).
//  - g reads: ONE broadcast ds_read_b128 per (b,c) (8 bf16) feeding 32 FMAs
//    (R3 diagnosis: 2x fp32 b128 per (b,c) at TA=2 made the per-CU LDS pipe
//    the bottleneck at ~20 us; this is 4x less LDS traffic per FMA).
//  - partials to a private coalesced ws slice; no atomics (R2 diagnosis).
// ---------------------------------------------------------------------------
template <int BCHUNK>
__global__ __launch_bounds__(256) void conv_partial(
        const float* __restrict__ feat,
        const float* __restrict__ geo,
        const float* __restrict__ W,
        float*       __restrict__ partial) {   // [NCHUNK][BATCH][NPTS][DOUT]
    constexpr int NCHUNK = NPTS / BCHUNK;
    __shared__ unsigned short g_lds[BCHUNK * NC * DOUT];  // bf16 bits
    __shared__ float bgeo[BCHUNK][4];

    const int t     = threadIdx.x;
    const int bid   = blockIdx.x;
    const int chunk = bid % NCHUNK;
    const int z     = bid / NCHUNK;

    const int b0 = chunk * BCHUNK;
    const float* geoz  = geo  + (size_t)z * NPTS * 3;
    const float* featz = feat + (size_t)z * NPTS * DIN;

    // ---- stage g[b,c,i] -> LDS (bf16); thread t owns (c,i) = (t>>3, t&7) ----
    const float4 w0 = *(const float4*)(W + t * 8);
    const float4 w1 = *(const float4*)(W + t * 8 + 4);
#pragma unroll
    for (int b = 0; b < BCHUNK; ++b) {
        const float* f = featz + (b0 + b) * DIN;   // wave-uniform -> s_load
        float s = fmaf(w0.x, f[0],
                  fmaf(w0.y, f[1],
                  fmaf(w0.z, f[2],
                  fmaf(w0.w, f[3],
                  fmaf(w1.x, f[4],
                  fmaf(w1.y, f[5],
                  fmaf(w1.z, f[6],
                         w1.w * f[7])))))));
        g_lds[b * (NC * DOUT) + t] = pack_bf16(s);
    }
    if (t < BCHUNK) {
        bgeo[t][0] = geoz[(b0 + t) * 3 + 0];
        bgeo[t][1] = geoz[(b0 + t) * 3 + 1];
        bgeo[t][2] = geoz[(b0 + t) * 3 + 2];
    }
    __syncthreads();

    // ---- main loop: thread t handles a_k = k*256 + t, k = 0..3 ----
    float ax[TA], ay[TA], az[TA];
#pragma unroll
    for (int k = 0; k < TA; ++k) {
        int a = k * 256 + t;
        ax[k] = geoz[a * 3 + 0];
        ay[k] = geoz[a * 3 + 1];
        az[k] = geoz[a * 3 + 2];
    }

    const float invw = (float)(NC - 1) / 3.5f;

    float acc[TA][DOUT];
#pragma unroll
    for (int k = 0; k < TA; ++k)
#pragma unroll
        for (int i = 0; i < DOUT; ++i) acc[k][i] = 0.f;

#pragma unroll 1
    for (int b = 0; b < BCHUNK; ++b) {
        const float bx = bgeo[b][0];
        const float by = bgeo[b][1];
        const float bz = bgeo[b][2];
        float u[TA];
#pragma unroll
        for (int k = 0; k < TA; ++k) {
            float dx = bx - ax[k], dy = by - ay[k], dz = bz - az[k];
            u[k] = sqrtf(fmaf(dx, dx, fmaf(dy, dy, fmaf(dz, dz, 1e-12f)))) * invw;
        }
        const uint4* gb = (const uint4*)&g_lds[b * (NC * DOUT)];
#pragma unroll
        for (int c = 0; c < NC; ++c) {
            float e[TA];
#pragma unroll
            for (int k = 0; k < TA; ++k) {
                float tt = u[k] - (float)c;
                e[k] = __expf(-(tt * tt));
            }
            uint4 q = gb[c];                        // broadcast ds_read_b128
            float gf[DOUT];
            gf[0] = __uint_as_float(q.x << 16);
            gf[1] = __uint_as_float(q.x & 0xffff0000u);
            gf[2] = __uint_as_float(q.y << 16);
            gf[3] = __uint_as_float(q.y & 0xffff0000u);
            gf[4] = __uint_as_float(q.z << 16);
            gf[5] = __uint_as_float(q.z & 0xffff0000u);
            gf[6] = __uint_as_float(q.w << 16);
            gf[7] = __uint_as_float(q.w & 0xffff0000u);
#pragma unroll
            for (int k = 0; k < TA; ++k)
#pragma unroll
                for (int i = 0; i < DOUT; ++i)
                    acc[k][i] = fmaf(e[k], gf[i], acc[k][i]);
        }
    }

    // ---- epilogue: private coalesced float4 stores ----
#pragma unroll
    for (int k = 0; k < TA; ++k) {
        int a = k * 256 + t;
        float* p = partial + (size_t)chunk * OUT_ELEMS + ((size_t)(z * NPTS + a)) * DOUT;
        ((float4*)p)[0] = make_float4(acc[k][0], acc[k][1], acc[k][2], acc[k][3]);
        ((float4*)p)[1] = make_float4(acc[k][4], acc[k][5], acc[k][6], acc[k][7]);
    }
}

// ---------------------------------------------------------------------------
// reduce_partials: out = scale * sum over chunks. float4 lanes, coalesced.
// ---------------------------------------------------------------------------
__global__ __launch_bounds__(256) void reduce_partials(
        const float* __restrict__ partial,
        const int*   __restrict__ n_norm,
        float*       __restrict__ out,
        int nchunk) {
    int e = blockIdx.x * blockDim.x + threadIdx.x;   // float4 index
    if (e >= OUT_ELEMS / 4) return;
    const float4* p = (const float4*)partial;
    float4 s = make_float4(0.f, 0.f, 0.f, 0.f);
#pragma unroll 8
    for (int c = 0; c < nchunk; ++c) {
        float4 v = p[(size_t)c * (OUT_ELEMS / 4) + e];
        s.x += v.x; s.y += v.y; s.z += v.z; s.w += v.w;
    }
    float scale = 1.0f / sqrtf((float)n_norm[0]);
    ((float4*)out)[e] = make_float4(s.x * scale, s.y * scale, s.z * scale, s.w * scale);
}

// ---------------------------------------------------------------------------
extern "C" void kernel_launch(void* const* d_in, const int* in_sizes, int n_in,
                              void* d_out, int out_size, void* d_ws, size_t ws_size,
                              hipStream_t stream) {
    const float* feat   = (const float*)d_in[0];   // [2,1024,8]
    const float* geo    = (const float*)d_in[1];   // [2,1024,3]
    const float* W      = (const float*)d_in[2];   // [32,8,8]
    const int*   n_norm = (const int*)  d_in[3];   // scalar 1024
    float* out     = (float*)d_out;                // [2,1024,8]
    float* partial = (float*)d_ws;

    const size_t need = (size_t)(NPTS / 4) * OUT_ELEMS * sizeof(float);  // 16 MB
    if (ws_size >= need) {
        constexpr int BCHUNK = 4, NCHUNK = NPTS / BCHUNK;            // 256 chunks
        conv_partial<BCHUNK><<<BATCH * NCHUNK, 256, 0, stream>>>(feat, geo, W, partial);
        reduce_partials<<<(OUT_ELEMS / 4 + 255) / 256, 256, 0, stream>>>(
            partial, n_norm, out, NCHUNK);
    } else {                                                          // 2 MB fallback
        constexpr int BCHUNK = 32, NCHUNK = NPTS / BCHUNK;
        conv_partial<BCHUNK><<<BATCH * NCHUNK, 256, 0, stream>>>(feat, geo, W, partial);
        reduce_partials<<<(OUT_ELEMS / 4 + 255) / 256, 256, 0, stream>>>(
            partial, n_norm, out, NCHUNK);
    }
}

// Round 6
// 91.047 us; speedup vs baseline: 1.1762x; 1.1762x over previous
//
#include <hip/hip_runtime.h>
#include <math.h>

#define BATCH 2
#define NPTS  1024
#define NC    32
#define DIN   8
#define DOUT  8
#define TA    4                               // a's per thread
#define OUT_ELEMS (BATCH * NPTS * DOUT)       // 16384
#define NE4   (OUT_ELEMS / 4)                 // 4096 float4 outputs

// RNE pack fp32 -> bf16 bits (no dependence on __hip_bfloat16 API).
__device__ __forceinline__ unsigned short pack_bf16(float s) {
    unsigned u = __float_as_uint(s);
    u += 0x7fffu + ((u >> 16) & 1u);          // round-to-nearest-even
    return (unsigned short)(u >> 16);
}

// ---------------------------------------------------------------------------
// conv_partial (UNCHANGED from R5 — measured good): block = (z, chunk).
// Stage g[b,c,i] (bf16) into LDS; thread t accumulates TA=4 a's over (b,c).
// One broadcast ds_read_b128 per (b,c) feeds 32 FMAs -> LDS pipe ~35%,
// VALU-bound. Partials to private coalesced ws slice; no atomics.
// ---------------------------------------------------------------------------
template <int BCHUNK>
__global__ __launch_bounds__(256) void conv_partial(
        const float* __restrict__ feat,
        const float* __restrict__ geo,
        const float* __restrict__ W,
        float*       __restrict__ partial) {   // [NCHUNK][BATCH][NPTS][DOUT]
    constexpr int NCHUNK = NPTS / BCHUNK;
    __shared__ unsigned short g_lds[BCHUNK * NC * DOUT];  // bf16 bits
    __shared__ float bgeo[BCHUNK][4];

    const int t     = threadIdx.x;
    const int bid   = blockIdx.x;
    const int chunk = bid % NCHUNK;
    const int z     = bid / NCHUNK;

    const int b0 = chunk * BCHUNK;
    const float* geoz  = geo  + (size_t)z * NPTS * 3;
    const float* featz = feat + (size_t)z * NPTS * DIN;

    const float4 w0 = *(const float4*)(W + t * 8);
    const float4 w1 = *(const float4*)(W + t * 8 + 4);
#pragma unroll
    for (int b = 0; b < BCHUNK; ++b) {
        const float* f = featz + (b0 + b) * DIN;   // wave-uniform -> s_load
        float s = fmaf(w0.x, f[0],
                  fmaf(w0.y, f[1],
                  fmaf(w0.z, f[2],
                  fmaf(w0.w, f[3],
                  fmaf(w1.x, f[4],
                  fmaf(w1.y, f[5],
                  fmaf(w1.z, f[6],
                         w1.w * f[7])))))));
        g_lds[b * (NC * DOUT) + t] = pack_bf16(s);
    }
    if (t < BCHUNK) {
        bgeo[t][0] = geoz[(b0 + t) * 3 + 0];
        bgeo[t][1] = geoz[(b0 + t) * 3 + 1];
        bgeo[t][2] = geoz[(b0 + t) * 3 + 2];
    }
    __syncthreads();

    float ax[TA], ay[TA], az[TA];
#pragma unroll
    for (int k = 0; k < TA; ++k) {
        int a = k * 256 + t;
        ax[k] = geoz[a * 3 + 0];
        ay[k] = geoz[a * 3 + 1];
        az[k] = geoz[a * 3 + 2];
    }

    const float invw = (float)(NC - 1) / 3.5f;

    float acc[TA][DOUT];
#pragma unroll
    for (int k = 0; k < TA; ++k)
#pragma unroll
        for (int i = 0; i < DOUT; ++i) acc[k][i] = 0.f;

#pragma unroll 1
    for (int b = 0; b < BCHUNK; ++b) {
        const float bx = bgeo[b][0];
        const float by = bgeo[b][1];
        const float bz = bgeo[b][2];
        float u[TA];
#pragma unroll
        for (int k = 0; k < TA; ++k) {
            float dx = bx - ax[k], dy = by - ay[k], dz = bz - az[k];
            u[k] = sqrtf(fmaf(dx, dx, fmaf(dy, dy, fmaf(dz, dz, 1e-12f)))) * invw;
        }
        const uint4* gb = (const uint4*)&g_lds[b * (NC * DOUT)];
#pragma unroll
        for (int c = 0; c < NC; ++c) {
            float e[TA];
#pragma unroll
            for (int k = 0; k < TA; ++k) {
                float tt = u[k] - (float)c;
                e[k] = __expf(-(tt * tt));
            }
            uint4 q = gb[c];                        // broadcast ds_read_b128
            float gf[DOUT];
            gf[0] = __uint_as_float(q.x << 16);
            gf[1] = __uint_as_float(q.x & 0xffff0000u);
            gf[2] = __uint_as_float(q.y << 16);
            gf[3] = __uint_as_float(q.y & 0xffff0000u);
            gf[4] = __uint_as_float(q.z << 16);
            gf[5] = __uint_as_float(q.z & 0xffff0000u);
            gf[6] = __uint_as_float(q.w << 16);
            gf[7] = __uint_as_float(q.w & 0xffff0000u);
#pragma unroll
            for (int k = 0; k < TA; ++k)
#pragma unroll
                for (int i = 0; i < DOUT; ++i)
                    acc[k][i] = fmaf(e[k], gf[i], acc[k][i]);
        }
    }

#pragma unroll
    for (int k = 0; k < TA; ++k) {
        int a = k * 256 + t;
        float* p = partial + (size_t)chunk * OUT_ELEMS + ((size_t)(z * NPTS + a)) * DOUT;
        ((float4*)p)[0] = make_float4(acc[k][0], acc[k][1], acc[k][2], acc[k][3]);
        ((float4*)p)[1] = make_float4(acc[k][4], acc[k][5], acc[k][6], acc[k][7]);
    }
}

// ---------------------------------------------------------------------------
// reduce_partials v2: R5's version had a 16-BLOCK grid and a 256-deep serial
// load chain per thread (latency-bound, est ~40 us). Now: 256 blocks, block =
// 16 float4-elems x 16 chunk-groups; each thread sums NCHUNK/16 INDEPENDENT
// loads (all outstanding together), then 16-way LDS reduction.
// ---------------------------------------------------------------------------
template <int NCHUNK>
__global__ __launch_bounds__(256) void reduce_partials(
        const float* __restrict__ partial,
        const int*   __restrict__ n_norm,
        float*       __restrict__ out) {
    const int tx = threadIdx.x & 15;          // f4 elem within block
    const int ty = threadIdx.x >> 4;          // chunk group 0..15
    const int e4 = blockIdx.x * 16 + tx;      // 0..NE4-1
    const float4* p = (const float4*)partial;

    float4 s = make_float4(0.f, 0.f, 0.f, 0.f);
#pragma unroll
    for (int j = 0; j < NCHUNK / 16; ++j) {   // independent loads, co-issued
        float4 v = p[(size_t)(j * 16 + ty) * NE4 + e4];
        s.x += v.x; s.y += v.y; s.z += v.z; s.w += v.w;
    }

    __shared__ float4 red[16][16];
    red[ty][tx] = s;
    __syncthreads();

    if (ty == 0) {
        float4 tot = red[0][tx];
#pragma unroll
        for (int j = 1; j < 16; ++j) {
            float4 v = red[j][tx];
            tot.x += v.x; tot.y += v.y; tot.z += v.z; tot.w += v.w;
        }
        const float scale = 1.0f / sqrtf((float)n_norm[0]);
        ((float4*)out)[e4] = make_float4(tot.x * scale, tot.y * scale,
                                         tot.z * scale, tot.w * scale);
    }
}

// ---------------------------------------------------------------------------
extern "C" void kernel_launch(void* const* d_in, const int* in_sizes, int n_in,
                              void* d_out, int out_size, void* d_ws, size_t ws_size,
                              hipStream_t stream) {
    const float* feat   = (const float*)d_in[0];   // [2,1024,8]
    const float* geo    = (const float*)d_in[1];   // [2,1024,3]
    const float* W      = (const float*)d_in[2];   // [32,8,8]
    const int*   n_norm = (const int*)  d_in[3];   // scalar 1024
    float* out     = (float*)d_out;                // [2,1024,8]
    float* partial = (float*)d_ws;

    const size_t need = (size_t)(NPTS / 4) * OUT_ELEMS * sizeof(float);  // 16 MB
    if (ws_size >= need) {
        constexpr int BCHUNK = 4, NCHUNK = NPTS / BCHUNK;            // 256 chunks
        conv_partial<BCHUNK><<<BATCH * NCHUNK, 256, 0, stream>>>(feat, geo, W, partial);
        reduce_partials<NCHUNK><<<NE4 / 16, 256, 0, stream>>>(partial, n_norm, out);
    } else {                                                          // 2 MB fallback
        constexpr int BCHUNK = 32, NCHUNK = NPTS / BCHUNK;           // 32 chunks
        conv_partial<BCHUNK><<<BATCH * NCHUNK, 256, 0, stream>>>(feat, geo, W, partial);
        reduce_partials<NCHUNK><<<NE4 / 16, 256, 0, stream>>>(partial, n_norm, out);
    }
}

// Round 8
// 80.022 us; speedup vs baseline: 1.3383x; 1.1378x over previous
//
#include <hip/hip_runtime.h>
#include <math.h>

#define BATCH 2
#define NPTS  1024
#define NC    32
#define DIN   8
#define DOUT  8
#define ATILE 64                          // a's per block (4 waves x 16)
#define NCHUNK 32                         // b-splits
#define BPW   (NPTS / NCHUNK)             // 32 b's per block
#define OUT_ELEMS (BATCH * NPTS * DOUT)   // 16384
#define NE4   (OUT_ELEMS / 4)             // 4096

typedef _Float16 half8 __attribute__((ext_vector_type(8)));
typedef float    floatx4 __attribute__((ext_vector_type(4)));

// ---------------------------------------------------------------------------
// conv_mfma: out[a,i] += sum_b sum_c E_b[a,c] * G_b[c,i]  ==  per-b K=32 MFMA.
//  - R7 NaN root cause: exp-recurrence step ratio exp(2*t0-1) overflowed to
//    inf at clamped t0=50 while the seed underflowed to 0 -> 0*inf = NaN in
//    the A-frag. (Plus a latent seed-underflow bug for t0 in (9.3,16.3).)
//  - Fix: DIRECT exps, e_j = expf(-(u-c_j)^2). Always finite: -(t^2) is
//    finite-negative, underflow->0 is the mathematically correct value.
//    Costs ~8 trans/lane/b (~+4us worst case) for zero numerics risk.
//  - Layouts (guide-verified): A: m=lane&15, k=quad*8+j (m120); B mirrored
//    (n=lane&15, k=quad*8+j); C/D: col=lane&15, row=quad*4+reg (m89).
//  - B-frag slots with n>=8 zero-filled (i only spans 0..7).
// ---------------------------------------------------------------------------
__global__ __launch_bounds__(256, 4) void conv_mfma(
        const float* __restrict__ feat,
        const float* __restrict__ geo,
        const float* __restrict__ W,
        float*       __restrict__ partial) {  // [NCHUNK][BATCH*NPTS][DOUT]
    __shared__ half8  g_frag[BPW * 64];       // 32 KB: B-frags, [b][lane]
    __shared__ float4 bgeo[BPW];              // 512 B

    const int t     = threadIdx.x;
    const int bid   = blockIdx.x;
    const int chunk = bid & (NCHUNK - 1);
    const int atile = (bid >> 5) & 15;
    const int z     = bid >> 9;

    const int b0 = chunk * BPW;
    const float* geoz  = geo  + (size_t)z * NPTS * 3;
    const float* featz = feat + (size_t)z * NPTS * DIN;

    // ---- zero the never-staged half of each B-frag (n>=8 slots) ----
    for (int s = t; s < BPW * 64; s += 256)
        if (s & 8) {                           // slot's n-index >= 8
            half8 zz = {};
            g_frag[s] = zz;
        }

    // ---- stage b geometry ----
    if (t < BPW)
        bgeo[t] = make_float4(geoz[(b0 + t) * 3 + 0],
                              geoz[(b0 + t) * 3 + 1],
                              geoz[(b0 + t) * 3 + 2], 0.f);

    // ---- stage G B-frags: thread t -> i = t&7, c-octet = (t>>3)&3, 8 b's ----
    {
        const int i   = t & 7;
        const int oct = (t >> 3) & 3;
        const int bl  = t >> 5;                // 0..7
        float4 wreg[8][2];
#pragma unroll
        for (int j = 0; j < 8; ++j) {          // W[c][i][0..7], c = oct*8+j
            const float* wr = W + ((oct * 8 + j) * DOUT + i) * DIN;
            wreg[j][0] = *(const float4*)wr;
            wreg[j][1] = *(const float4*)(wr + 4);
        }
#pragma unroll
        for (int pass = 0; pass < BPW / 8; ++pass) {
            const int b = pass * 8 + bl;
            const float* f = featz + (size_t)(b0 + b) * DIN;
            const float4 f0 = *(const float4*)f;
            const float4 f1 = *(const float4*)(f + 4);
            half8 gv;
#pragma unroll
            for (int j = 0; j < 8; ++j) {
                float s = fmaf(wreg[j][0].x, f0.x,
                          fmaf(wreg[j][0].y, f0.y,
                          fmaf(wreg[j][0].z, f0.z,
                          fmaf(wreg[j][0].w, f0.w,
                          fmaf(wreg[j][1].x, f1.x,
                          fmaf(wreg[j][1].y, f1.y,
                          fmaf(wreg[j][1].z, f1.z,
                                 wreg[j][1].w * f1.w)))))));
                gv[j] = (_Float16)s;           // k-order j: same convention as A
            }
            g_frag[b * 64 + oct * 16 + i] = gv;
        }
    }
    __syncthreads();

    // ---- main loop: wave wv handles a-subtile a0 = atile*64 + wv*16 ----
    const int lane = t & 63;
    const int wv   = t >> 6;
    const int m    = lane & 15;                // A-row = a-local
    const int quad = lane >> 4;
    const int a0   = atile * ATILE + wv * 16;
    const int a    = a0 + m;

    const float ax = geoz[a * 3 + 0];
    const float ay = geoz[a * 3 + 1];
    const float az = geoz[a * 3 + 2];
    const float c0   = (float)(quad * 8);      // lane's c-octet start
    const float invw = (float)(NC - 1) / 3.5f;

    floatx4 acc = {0.f, 0.f, 0.f, 0.f};

#pragma unroll 4
    for (int b = 0; b < BPW; ++b) {
        const float4 bg = bgeo[b];             // broadcast ds_read
        const float dx = bg.x - ax, dy = bg.y - ay, dz = bg.z - az;
        const float u = sqrtf(fmaf(dx, dx, fmaf(dy, dy, fmaf(dz, dz, 1e-12f)))) * invw;
        const float t0 = u - c0;
        half8 af;
#pragma unroll
        for (int j = 0; j < 8; ++j) {
            float tj = t0 - (float)j;
            af[j] = (_Float16)__expf(-(tj * tj));   // always finite, no NaN path
        }
        const half8 bfrg = g_frag[b * 64 + lane];   // per-lane ds_read_b128
        acc = __builtin_amdgcn_mfma_f32_16x16x32_f16(af, bfrg, acc, 0, 0, 0);
    }

    // ---- epilogue: D col = i (lane&15, keep <8), row = quad*4 + reg ----
    if (m < 8) {
        float* p = partial + (size_t)chunk * OUT_ELEMS
                 + ((size_t)(z * NPTS + a0 + quad * 4)) * DOUT + m;
#pragma unroll
        for (int r = 0; r < 4; ++r)
            p[r * DOUT] = acc[r];
    }
}

// ---------------------------------------------------------------------------
// reduce_partials: 256 blocks, block = 16 f4-elems x 16 chunk-groups; each
// thread sums NCHUNK/16 independent loads, then 16-way LDS reduction.
// ---------------------------------------------------------------------------
template <int NCH>
__global__ __launch_bounds__(256) void reduce_partials(
        const float* __restrict__ partial,
        const int*   __restrict__ n_norm,
        float*       __restrict__ out) {
    const int tx = threadIdx.x & 15;
    const int ty = threadIdx.x >> 4;
    const int e4 = blockIdx.x * 16 + tx;
    const float4* p = (const float4*)partial;

    float4 s = make_float4(0.f, 0.f, 0.f, 0.f);
#pragma unroll
    for (int j = 0; j < NCH / 16; ++j) {
        float4 v = p[(size_t)(j * 16 + ty) * NE4 + e4];
        s.x += v.x; s.y += v.y; s.z += v.z; s.w += v.w;
    }

    __shared__ float4 red[16][16];
    red[ty][tx] = s;
    __syncthreads();

    if (ty == 0) {
        float4 tot = red[0][tx];
#pragma unroll
        for (int j = 1; j < 16; ++j) {
            float4 v = red[j][tx];
            tot.x += v.x; tot.y += v.y; tot.z += v.z; tot.w += v.w;
        }
        const float scale = 1.0f / sqrtf((float)n_norm[0]);
        ((float4*)out)[e4] = make_float4(tot.x * scale, tot.y * scale,
                                         tot.z * scale, tot.w * scale);
    }
}

// ---------------------------------------------------------------------------
extern "C" void kernel_launch(void* const* d_in, const int* in_sizes, int n_in,
                              void* d_out, int out_size, void* d_ws, size_t ws_size,
                              hipStream_t stream) {
    const float* feat   = (const float*)d_in[0];   // [2,1024,8]
    const float* geo    = (const float*)d_in[1];   // [2,1024,3]
    const float* W      = (const float*)d_in[2];   // [32,8,8]
    const int*   n_norm = (const int*)  d_in[3];   // scalar 1024
    float* out     = (float*)d_out;                // [2,1024,8]
    float* partial = (float*)d_ws;                 // 32 * 64 KB = 2 MB

    const int grid = BATCH * 16 * NCHUNK;          // 1024 blocks
    conv_mfma<<<grid, 256, 0, stream>>>(feat, geo, W, partial);
    reduce_partials<NCHUNK><<<NE4 / 16, 256, 0, stream>>>(partial, n_norm, out);
}